// Round 1
// baseline (234.601 us; speedup 1.0000x reference)
//
#include <hip/hip_runtime.h>
#include <hip/hip_fp16.h>

#define NN 50000
#define NE 800000
#define D  96
#define NB_SCAN 196   // ceil(NN/256)
#define N4 (NN * D / 4)
#define CB4 ((N4 + 255) / 256)
#define WFRAG_BLKS 5  // ceil(18*64/256)
#define EMAX (NE + 8 * NN)          // padded edge capacity (1.2M)
#define EZ4  (EMAX / 4)             // 300000 v4u words
#define EZB  ((EZ4 + 255) / 256)    // 1172
#define RB   3128                   // row-blocks per fblock: ceil(50000/16)=3125, padded to %8==0
#define NFB  3                      // feature blocks of 32 feats (3.2MB table each -> L2-resident)

typedef unsigned int   uint32;
typedef unsigned short uint16;
typedef short  v8s __attribute__((ext_vector_type(8)));  // 8 bf16 (4 VGPRs)
typedef float  v4f __attribute__((ext_vector_type(4)));  // MFMA accumulator
typedef unsigned int v2u __attribute__((ext_vector_type(2)));
typedef unsigned int v4u __attribute__((ext_vector_type(4)));
typedef float v2f __attribute__((ext_vector_type(2)));

__device__ inline uint16 f32_to_bf16(float f) {          // round-nearest-even
    uint32 u = __float_as_uint(f);
    u += 0x7FFF + ((u >> 16) & 1);
    return (uint16)(u >> 16);
}

__device__ inline void u1f(uint32 u, float& a, float& b) {
    a = __uint_as_float(u << 16);
    b = __uint_as_float(u & 0xFFFF0000u);
}

__device__ inline float f16_val(uint32 e) {
    __half_raw h; h.x = (uint16)(e >> 16);
    return __half2float(__half(h));
}

// ---- fused prep: H->bf16 | zero counts | W->B-frag layout | zero edges ----
__global__ void prep(const float4* __restrict__ H, ushort4* __restrict__ Hb,
                     const float* __restrict__ W, uint16* __restrict__ Wfrag,
                     int* __restrict__ counts, v4u* __restrict__ edges4) {
    int b = blockIdx.x;
    int t = threadIdx.x;
    if (b < CB4) {
        int i = b * 256 + t;
        if (i < N4) {
            float4 v = H[i];
            ushort4 o;
            o.x = f32_to_bf16(v.x); o.y = f32_to_bf16(v.y);
            o.z = f32_to_bf16(v.z); o.w = f32_to_bf16(v.w);
            Hb[i] = o;
        }
    } else if (b < CB4 + NB_SCAN) {
        int i = (b - CB4) * 256 + t;
        if (i < NN) counts[i] = 0;
    } else if (b < CB4 + NB_SCAN + WFRAG_BLKS) {
        int idx = (b - CB4 - NB_SCAN) * 256 + t;   // 0..1151 = bt*64+lane
        if (idx < 18 * 64) {
            int bt = idx >> 6, lane = idx & 63;
            int nt = bt / 3, kc = bt % 3;
            int col = nt * 16 + (lane & 15);
            int kbase = kc * 32 + (lane >> 4) * 8;
            uint16 tmp[8];
            #pragma unroll
            for (int j = 0; j < 8; ++j) tmp[j] = f32_to_bf16(W[(kbase + j) * D + col]);
            uint32* dst = (uint32*)(Wfrag + ((size_t)bt * 64 + lane) * 8);
            const uint32* src = (const uint32*)tmp;
            #pragma unroll
            for (int j = 0; j < 4; ++j) dst[j] = src[j];
        }
    } else {
        int i = (b - CB4 - NB_SCAN - WFRAG_BLKS) * 256 + t;
        if (i < EZ4) edges4[i] = (v4u){0u, 0u, 0u, 0u};
    }
}

// ---------------- CSR build (two-phase, slot-based, 8-padded rows) ----------
// 2 edges per thread.
__global__ void hist_slots(const int* __restrict__ rows, int* __restrict__ counts,
                           int* __restrict__ slot) {
    int base = (blockIdx.x * blockDim.x + threadIdx.x) * 2;
    if (base < NE) {
        v2u rr = *(const v2u*)(rows + base);
        slot[base]     = atomicAdd(&counts[rr.x], 1);
        slot[base + 1] = atomicAdd(&counts[rr.y], 1);
    }
}

__global__ void scan_p1(const int* __restrict__ counts, int* __restrict__ partials) {
    __shared__ int red[256];
    int t = threadIdx.x;
    int i = blockIdx.x * 256 + t;
    red[t] = (i < NN) ? ((counts[i] + 7) & ~7) : 0;   // padded counts
    __syncthreads();
    for (int off = 128; off > 0; off >>= 1) {
        if (t < off) red[t] += red[t + off];
        __syncthreads();
    }
    if (t == 0) partials[blockIdx.x] = red[0];
}

__global__ void scan_p23(const int* __restrict__ counts, const int* __restrict__ partials,
                         int* __restrict__ row_ptr) {
    __shared__ int pp[256];
    __shared__ int sh[256];
    int t = threadIdx.x;
    pp[t] = (t < NB_SCAN) ? partials[t] : 0;
    __syncthreads();
    for (int off = 1; off < 256; off <<= 1) {
        int u = (t >= off) ? pp[t - off] : 0;
        __syncthreads();
        pp[t] += u;
        __syncthreads();
    }
    int blk_off = (blockIdx.x == 0) ? 0 : pp[blockIdx.x - 1];
    int i = blockIdx.x * 256 + t;
    int v = (i < NN) ? ((counts[i] + 7) & ~7) : 0;    // padded counts
    sh[t] = v;
    __syncthreads();
    for (int off = 1; off < 256; off <<= 1) {
        int u = (t >= off) ? sh[t - off] : 0;
        __syncthreads();
        sh[t] += u;
        __syncthreads();
    }
    int excl = sh[t] - v + blk_off;
    if (i < NN) row_ptr[i] = excl;
    if (i == NN - 1) row_ptr[NN] = excl + v;
}

// edge = col (low 16) | f16(val) (high 16); p = row_ptr[row] + slot. 2/thread.
__global__ void fill_edges(const int* __restrict__ rows, const int* __restrict__ cols,
                           const float* __restrict__ vals, const int* __restrict__ row_ptr,
                           const int* __restrict__ slot, uint32* __restrict__ edges) {
    int base = (blockIdx.x * blockDim.x + threadIdx.x) * 2;
    if (base < NE) {
        v2u rr = *(const v2u*)(rows + base);
        v2u cc = *(const v2u*)(cols + base);
        v2f vv = *(const v2f*)(vals + base);
        v2u ss = *(const v2u*)(slot + base);
        __half_raw h0 = __half_raw(__float2half(vv.x));
        __half_raw h1 = __half_raw(__float2half(vv.y));
        edges[row_ptr[rr.x] + ss.x] = (cc.x & 0xFFFF) | ((uint32)h0.x << 16);
        edges[row_ptr[rr.y] + ss.y] = (cc.y & 0xFFFF) | ((uint32)h1.x << 16);
    }
}

// ---- feature-blocked SpMM: Yb[:,fb*32:(fb+1)*32] = bf16( sum val * Xb[col, fb-chunk] )
// Grid = NFB * RB blocks; fb slowest so all concurrently-resident blocks share one
// 3.2MB L2-resident gather table chunk. RB%8==0 keeps rb->XCD mapping identical
// across fb so each XCD re-reads the same edge slice from its own L2.
// 16 lanes/row (4B gathers = 1 cacheline per edge-row), 16 rows/block, all lanes active.
__global__ void spmm(const int* __restrict__ row_ptr, const uint32* __restrict__ edges,
                     const uint16* __restrict__ Xb, uint16* __restrict__ Yb) {
    int tid  = threadIdx.x;
    int lane = tid & 15;
    int g    = tid >> 4;
    int bid  = blockIdx.x;
    int fb   = bid / RB;
    int rb   = bid - fb * RB;
    int r    = rb * 16 + g;
    if (r >= NN) return;

    const uint32* xbase = (const uint32*)(Xb + fb * 32) + lane;   // + col*48

    float a0 = 0.f, a1 = 0.f;
    int s = row_ptr[r];
    int e = row_ptr[r + 1];
    int i = s;
    for (; i + 15 < e; i += 16) {
        v4u e0 = *(const v4u*)(edges + i);
        v4u e1 = *(const v4u*)(edges + i + 4);
        v4u e2 = *(const v4u*)(edges + i + 8);
        v4u e3 = *(const v4u*)(edges + i + 12);
        uint32 ee[16] = {e0.x,e0.y,e0.z,e0.w, e1.x,e1.y,e1.z,e1.w,
                         e2.x,e2.y,e2.z,e2.w, e3.x,e3.y,e3.z,e3.w};
        uint32 xx[16];
        #pragma unroll
        for (int j = 0; j < 16; ++j)
            xx[j] = xbase[(size_t)(ee[j] & 0xFFFF) * 48];
        #pragma unroll
        for (int j = 0; j < 16; ++j) {
            float v = f16_val(ee[j]);
            float x0, x1;
            u1f(xx[j], x0, x1);
            a0 += v * x0; a1 += v * x1;
        }
    }
    for (; i < e; i += 8) {
        v4u ea = *(const v4u*)(edges + i);
        v4u eb = *(const v4u*)(edges + i + 4);
        uint32 ee[8] = {ea.x, ea.y, ea.z, ea.w, eb.x, eb.y, eb.z, eb.w};
        uint32 xx[8];
        #pragma unroll
        for (int j = 0; j < 8; ++j)
            xx[j] = xbase[(size_t)(ee[j] & 0xFFFF) * 48];
        #pragma unroll
        for (int j = 0; j < 8; ++j) {
            float v = f16_val(ee[j]);
            float x0, x1;
            u1f(xx[j], x0, x1);
            a0 += v * x0; a1 += v * x1;
        }
    }

    uint32 o = (uint32)f32_to_bf16(a0) | ((uint32)f32_to_bf16(a1) << 16);
    __builtin_nontemporal_store(o, (uint32*)Yb + (size_t)r * 48 + fb * 16 + lane);
}

// ---- fused pass 3 (feature-blocked): Sb = bf16( 12*U1 - 40*U2 + 32 * P U2 ) ----
__global__ void spmm_fuse(const int* __restrict__ row_ptr, const uint32* __restrict__ edges,
                          const uint16* __restrict__ U1, const uint16* __restrict__ U2,
                          uint16* __restrict__ Sb) {
    int tid  = threadIdx.x;
    int lane = tid & 15;
    int g    = tid >> 4;
    int bid  = blockIdx.x;
    int fb   = bid / RB;
    int rb   = bid - fb * RB;
    int r    = rb * 16 + g;
    if (r >= NN) return;

    const uint32* xbase = (const uint32*)(U2 + fb * 32) + lane;   // gather operand = U2

    float a0 = 0.f, a1 = 0.f;
    int s = row_ptr[r];
    int e = row_ptr[r + 1];
    int i = s;
    for (; i + 15 < e; i += 16) {
        v4u e0 = *(const v4u*)(edges + i);
        v4u e1 = *(const v4u*)(edges + i + 4);
        v4u e2 = *(const v4u*)(edges + i + 8);
        v4u e3 = *(const v4u*)(edges + i + 12);
        uint32 ee[16] = {e0.x,e0.y,e0.z,e0.w, e1.x,e1.y,e1.z,e1.w,
                         e2.x,e2.y,e2.z,e2.w, e3.x,e3.y,e3.z,e3.w};
        uint32 xx[16];
        #pragma unroll
        for (int j = 0; j < 16; ++j)
            xx[j] = xbase[(size_t)(ee[j] & 0xFFFF) * 48];
        #pragma unroll
        for (int j = 0; j < 16; ++j) {
            float v = f16_val(ee[j]);
            float x0, x1;
            u1f(xx[j], x0, x1);
            a0 += v * x0; a1 += v * x1;
        }
    }
    for (; i < e; i += 8) {
        v4u ea = *(const v4u*)(edges + i);
        v4u eb = *(const v4u*)(edges + i + 4);
        uint32 ee[8] = {ea.x, ea.y, ea.z, ea.w, eb.x, eb.y, eb.z, eb.w};
        uint32 xx[8];
        #pragma unroll
        for (int j = 0; j < 8; ++j)
            xx[j] = xbase[(size_t)(ee[j] & 0xFFFF) * 48];
        #pragma unroll
        for (int j = 0; j < 8; ++j) {
            float v = f16_val(ee[j]);
            float x0, x1;
            u1f(xx[j], x0, x1);
            a0 += v * x0; a1 += v * x1;
        }
    }

    uint32 w1 = ((const uint32*)U1)[(size_t)r * 48 + fb * 16 + lane];
    uint32 w2 = xbase[(size_t)r * 48];
    float p0, p1, q0, q1;
    u1f(w1, p0, p1);
    u1f(w2, q0, q1);
    float s0 = 12.f*p0 - 40.f*q0 + 32.f*a0;
    float s1 = 12.f*p1 - 40.f*q1 + 32.f*a1;

    uint32 o = (uint32)f32_to_bf16(s0) | ((uint32)f32_to_bf16(s1) << 16);
    __builtin_nontemporal_store(o, (uint32*)Sb + (size_t)r * 48 + fb * 16 + lane);
}

// ---- out = Sb @ W + bias via MFMA; one wave per 16-row strip (grid-stride) --
__global__ void mfma_gemm(const uint16* __restrict__ Sb, const uint16* __restrict__ Wfrag,
                          const float* __restrict__ bias, float* __restrict__ out) {
    int tid   = threadIdx.x;
    int lane  = tid & 63;
    int wv    = blockIdx.x * (blockDim.x >> 6) + (tid >> 6);
    int nwv   = gridDim.x * (blockDim.x >> 6);
    int col   = lane & 15;
    int quad  = lane >> 4;

    v8s wf[6][3];
    #pragma unroll
    for (int nt = 0; nt < 6; ++nt)
        #pragma unroll
        for (int kc = 0; kc < 3; ++kc)
            wf[nt][kc] = ((const v8s*)Wfrag)[(nt * 3 + kc) * 64 + lane];

    float bi[6];
    #pragma unroll
    for (int nt = 0; nt < 6; ++nt) bi[nt] = bias[nt * 16 + col];

    for (int s = wv; s < NN / 16; s += nwv) {
        int r0 = s * 16;
        const uint16* arow = Sb + (size_t)(r0 + col) * D + quad * 8;
        v8s a0 = *((const v8s*)(arow));
        v8s a1 = *((const v8s*)(arow + 32));
        v8s a2 = *((const v8s*)(arow + 64));
        v4f acc[6];
        #pragma unroll
        for (int nt = 0; nt < 6; ++nt) {
            v4f c = {0.f, 0.f, 0.f, 0.f};
            c = __builtin_amdgcn_mfma_f32_16x16x32_bf16(a0, wf[nt][0], c, 0, 0, 0);
            c = __builtin_amdgcn_mfma_f32_16x16x32_bf16(a1, wf[nt][1], c, 0, 0, 0);
            c = __builtin_amdgcn_mfma_f32_16x16x32_bf16(a2, wf[nt][2], c, 0, 0, 0);
            acc[nt] = c;
        }
        #pragma unroll
        for (int nt = 0; nt < 6; ++nt) {
            float* o = out + (size_t)(r0 + quad * 4) * D + nt * 16 + col;
            __builtin_nontemporal_store(acc[nt][0] + bi[nt], o + 0 * D);
            __builtin_nontemporal_store(acc[nt][1] + bi[nt], o + 1 * D);
            __builtin_nontemporal_store(acc[nt][2] + bi[nt], o + 2 * D);
            __builtin_nontemporal_store(acc[nt][3] + bi[nt], o + 3 * D);
        }
    }
}

extern "C" void kernel_launch(void* const* d_in, const int* in_sizes, int n_in,
                              void* d_out, int out_size, void* d_ws, size_t ws_size,
                              hipStream_t stream) {
    const int*   rows = (const int*)d_in[0];
    const int*   cols = (const int*)d_in[1];
    const float* vals = (const float*)d_in[2];
    const float* H    = (const float*)d_in[3];
    const float* W    = (const float*)d_in[4];
    const float* bias = (const float*)d_in[5];
    float* out = (float*)d_out;

    char* ws = (char*)d_ws;
    uint16* Hb       = (uint16*)ws;  ws += (size_t)NN * D * 2;   // 9.6 MB
    uint16* U1b      = (uint16*)ws;  ws += (size_t)NN * D * 2;
    uint16* U2b      = (uint16*)ws;  ws += (size_t)NN * D * 2;   // slot aliases here
    uint16* Sb       = (uint16*)ws;  ws += (size_t)NN * D * 2;
    uint32* edges    = (uint32*)ws;  ws += (size_t)EMAX * 4;     // 4.8 MB padded
    uint16* Wfrag    = (uint16*)ws;  ws += (size_t)18 * 64 * 8 * 2;
    int*    counts   = (int*)ws;     ws += (size_t)NN * 4;
    int*    row_ptr  = (int*)ws;     ws += (size_t)(NN + 1) * 4;
    int*    partials = (int*)ws;     ws += 256 * 4;
    int*    slot     = (int*)U2b;    // dead before spmm writes U2b

    const int eb2 = (NE / 2 + 255) / 256;   // 2 edges/thread

    prep<<<CB4 + NB_SCAN + WFRAG_BLKS + EZB, 256, 0, stream>>>(
        (const float4*)H, (ushort4*)Hb, W, Wfrag, counts, (v4u*)edges);
    hist_slots<<<eb2, 256, 0, stream>>>(rows, counts, slot);
    scan_p1<<<NB_SCAN, 256, 0, stream>>>(counts, partials);
    scan_p23<<<NB_SCAN, 256, 0, stream>>>(counts, partials, row_ptr);
    fill_edges<<<eb2, 256, 0, stream>>>(rows, cols, vals, row_ptr, slot, edges);

    // U1 = P H,  U2 = P U1,  Sb = 12U1 - 40U2 + 32 P U2  (= T0+T1+T2+T3)
    spmm<<<NFB * RB, 256, 0, stream>>>(row_ptr, edges, Hb,  U1b);
    spmm<<<NFB * RB, 256, 0, stream>>>(row_ptr, edges, U1b, U2b);
    spmm_fuse<<<NFB * RB, 256, 0, stream>>>(row_ptr, edges, U1b, U2b, Sb);
    // out = Sb @ W + bias
    mfma_gemm<<<782, 256, 0, stream>>>(Sb, Wfrag, bias, out);
}